// Round 1
// 231.873 us; speedup vs baseline: 1.0580x; 1.0580x over previous
//
#include <hip/hip_runtime.h>
#include <hip/hip_bf16.h>

// GCN 2-layer via CSR gather:
//   dis = rsqrt(indeg_by_dst + 1)
//   hs  = bf16( (x@W) * dis[row] )     (split-bf16 MFMA, fp32-accurate)
//   out[i] = act( dis[i] * (hs[i] + sum_{s in N(i)} hs[s]) + b )
// CSR build is a fully DETERMINISTIC two-pass multisplit (radix-sort style).
// GEMM is now MFMA (16x16x32 bf16) with 2-term split of X and W:
//   x@W = xh@Wh + xh@Wl + xl@Wh  (+ xl@Wl ~ 2^-18, dropped)
// so accuracy stays at fp32-GEMM level while compute moves to the matrix
// pipe (~3 us of MFMA vs ~10+ us vector-FMA floor). gemm reads X straight
// from global (each element exactly once), no LDS, no barriers. W is
// pre-split into fragment-linear bf16 hi/lo tables by block 0 of edge_hist.

#define FOUT 64
#define BW 256        // nodes per bucket
#define BSH 8
#define MAXB 512      // >= ceil(n/BW), power of 2
#define CHUNK 4096    // edges per hist/place block; nblk = ceil(E/CHUNK) <= 512
#define SLAB 6144     // slab capacity per bucket (mean 4092 for E=1.6M,B=391)

#define NT1 1024      // W1 frag tasks: (128/32)*4*64
#define NT2 512       // W2 frag tasks: (64/32)*4*64

__device__ __forceinline__ float bf2f(unsigned int u16) {
    union { unsigned int i; float f; } c;
    c.i = u16 << 16;
    return c.f;
}
__device__ __forceinline__ unsigned short f2bf(float f) {
    union { float f; unsigned int i; } c;
    c.f = f;
    unsigned int i = c.i;
    return (unsigned short)((i + 0x7FFFu + ((i >> 16) & 1u)) >> 16);  // RN-even
}

typedef __attribute__((ext_vector_type(8))) short short8v;  // 8 bf16 = 4 VGPR
typedef __attribute__((ext_vector_type(4))) float f32x4;    // MFMA acc

// ---- W -> fragment-linear bf16 hi/lo split ------------------------------
// task = ((s*4 + cf)*64 + lane); element j of lane's B-frag is
// W[s*32 + (lane>>4)*8 + j][cf*16 + (lane&15)]  (same k-mapping as A-frags,
// so any internal k-permutation of the MFMA cancels between A and B).
__device__ __forceinline__ void conv_w_frag(const float* __restrict__ W,
                                            unsigned short* __restrict__ WhF,
                                            unsigned short* __restrict__ WlF,
                                            int task) {
    const int lane = task & 63;
    const int cf = (task >> 6) & 3;
    const int s = task >> 8;
    const int q = lane >> 4, m = lane & 15;
#pragma unroll
    for (int j = 0; j < 8; j++) {
        int k = s * 32 + q * 8 + j;
        float x = W[(size_t)k * 64 + cf * 16 + m];
        unsigned short h = f2bf(x);
        WhF[(size_t)task * 8 + j] = h;
        WlF[(size_t)task * 8 + j] = f2bf(x - bf2f(h));
    }
}

// ---- pass A: per-block bucket histogram -> cnt[blk][bucket] --------------
// block 0 additionally pre-splits W1/W2 into frag-linear bf16 hi/lo tables
// (1536 tasks / 512 threads = 3 iters, ~0.3 us, hidden under other blocks).
__global__ __launch_bounds__(512) void edge_hist(
    const int* __restrict__ dst, int* __restrict__ cnt, int E,
    const float* __restrict__ W1, const float* __restrict__ W2,
    unsigned short* __restrict__ whf1, unsigned short* __restrict__ wlf1,
    unsigned short* __restrict__ whf2, unsigned short* __restrict__ wlf2) {
    __shared__ int h[MAXB];
    const int blk = blockIdx.x, t = threadIdx.x;
    h[t] = 0;
    __syncthreads();
    const int e0 = blk * CHUNK;
#pragma unroll
    for (int k = 0; k < CHUNK / 512; k++) {
        int e = e0 + k * 512 + t;
        if (e < E) atomicAdd(&h[dst[e] >> BSH], 1);
    }
    if (blk == 0) {
        for (int task = t; task < NT1 + NT2; task += 512) {
            if (task < NT1) conv_w_frag(W1, whf1, wlf1, task);
            else            conv_w_frag(W2, whf2, wlf2, task - NT1);
        }
    }
    __syncthreads();
    cnt[blk * MAXB + t] = h[t];
}

// ---- pass B: per-bucket exclusive scan over blocks -> absolute bases -----
__global__ __launch_bounds__(512) void col_scan(int* __restrict__ cnt, int nblk,
                                                int* __restrict__ gcnt) {
    __shared__ int ts[512];
    const int b = blockIdx.x;  // bucket
    const int t = threadIdx.x;
    int v = (t < nblk) ? cnt[t * MAXB + b] : 0;
    ts[t] = v;
    __syncthreads();
    for (int off = 1; off < 512; off <<= 1) {
        int x = (t >= off) ? ts[t - off] : 0;
        __syncthreads();
        ts[t] += x;
        __syncthreads();
    }
    if (t < nblk) cnt[t * MAXB + b] = b * SLAB + ts[t] - v;  // abs base
    if (t == 511) gcnt[b] = ts[511];                          // bucket total
}

// ---- pass C: placement at precomputed bases (no global atomics) ----------
__global__ __launch_bounds__(512) void edge_place(
    const int* __restrict__ src, const int* __restrict__ dst,
    const int* __restrict__ cnt, int* __restrict__ ebuf, int E) {
    __shared__ int lbase[MAXB];
    __shared__ int cur[MAXB];
    const int blk = blockIdx.x, t = threadIdx.x;
    lbase[t] = cnt[blk * MAXB + t];
    cur[t] = 0;
    __syncthreads();
    const int e0 = blk * CHUNK;
#pragma unroll
    for (int k = 0; k < CHUNK / 512; k++) {
        int e = e0 + k * 512 + t;
        if (e < E) {
            int d = dst[e];
            int b = d >> BSH;
            int r = atomicAdd(&cur[b], 1);  // LDS only
            ebuf[lbase[b] + r] = src[e] | ((d & (BW - 1)) << 17);  // src < 2^17
        }
    }
}

// ---- per-bucket finalize: degree/scan/dis/rowinfo, rank ebuf IN PLACE ----
__global__ __launch_bounds__(512) void csr_build(
    int* __restrict__ ebuf, const int* __restrict__ gcnt,
    unsigned int* __restrict__ rowinfo, float* __restrict__ dis, int n) {
    __shared__ int ldeg[BW];
    __shared__ int lscan[BW];
    const int b = blockIdx.x, t = threadIdx.x;
    const int node0 = b << BSH;
    const int nn = min(BW, n - node0);
    const int ebeg = b * SLAB;
    const int cnt = gcnt[b];

    // stage this bucket's edge words in registers (SLAB/512 = 12 max)
    int w[SLAB / 512];
#pragma unroll
    for (int k = 0; k < SLAB / 512; k++) {
        int idx = t + k * 512;
        w[k] = (idx < cnt) ? ebuf[ebeg + idx] : -1;
    }
    if (t < BW) ldeg[t] = 0;
    __syncthreads();
#pragma unroll
    for (int k = 0; k < SLAB / 512; k++)
        if (w[k] >= 0) atomicAdd(&ldeg[w[k] >> 17], 1);
    __syncthreads();
    int v = 0;
    if (t < BW) {
        v = ldeg[t];
        lscan[t] = v;
    }
    __syncthreads();
    for (int off = 1; off < BW; off <<= 1) {
        int x = 0;
        if (t < BW && t >= off) x = lscan[t - off];
        __syncthreads();
        if (t < BW) lscan[t] += x;
        __syncthreads();
    }
    if (t < nn) {
        int ex = lscan[t] - v;  // exclusive prefix within bucket
        rowinfo[node0 + t] = ((unsigned int)(ebeg + ex) << 8) | (unsigned int)v;
        dis[node0 + t] = rsqrtf((float)v + 1.0f);  // +1 self-loop
    }
    __syncthreads();
    if (t < BW) ldeg[t] = lscan[t] - v;  // reuse as write cursor
    __syncthreads();
    // all words are register-staged (barrier above) => in-place rewrite safe
#pragma unroll
    for (int k = 0; k < SLAB / 512; k++)
        if (w[k] >= 0) {
            int r = atomicAdd(&ldeg[w[k] >> 17], 1);
            ebuf[ebeg + r] = w[k] & 0x1FFFF;  // ebuf becomes col
        }
}

// ---- GEMM: HS[n x 64] = bf16( (X[n x K] @ W[K x 64]) * dis[row] ) --------
// Split-bf16 MFMA: 4 waves/block, wave owns 16 rows x 64 cols (4 col-frags,
// 16x16x32 bf16). A-frags read straight from global (each X elem exactly
// once per kernel), split to hi/lo in-register; B-frags from the
// frag-linear tables (L1/L2-resident, 16B/lane coalesced). No LDS, no
// __syncthreads. 3 MFMA per (kstep, col-frag): AhBh + AlBh + AhBl.
template <int K>
__global__ __launch_bounds__(256) void gemm_xw_mfma(
    const float* __restrict__ X,
    const unsigned short* __restrict__ WhF,
    const unsigned short* __restrict__ WlF,
    const float* __restrict__ dis,
    unsigned short* __restrict__ HS, int n) {
    const int lane = threadIdx.x & 63;
    const int wv = threadIdx.x >> 6;
    const int wrow0 = blockIdx.x * 64 + wv * 16;
    const int m = lane & 15;   // A: row-in-tile / B: col-in-frag / D: col
    const int q = lane >> 4;   // k-group (A/B), row-quad (D)

    f32x4 acc[4];
#pragma unroll
    for (int cf = 0; cf < 4; cf++) acc[cf] = (f32x4)0.f;

    const int arow = wrow0 + m;
    const bool rok = (arow < n);
    const float* xp = X + (size_t)arow * K + q * 8;

#pragma unroll
    for (int s = 0; s < K / 32; s++) {
        float4 v0, v1;
        if (rok) {
            v0 = *(const float4*)(xp + s * 32);
            v1 = *(const float4*)(xp + s * 32 + 4);
        } else {
            v0 = make_float4(0.f, 0.f, 0.f, 0.f);
            v1 = v0;
        }
        const float xa[8] = {v0.x, v0.y, v0.z, v0.w, v1.x, v1.y, v1.z, v1.w};
        union { unsigned int u[4]; short8v v; } Ah, Al;
#pragma unroll
        for (int p = 0; p < 4; p++) {
            unsigned short h0 = f2bf(xa[2 * p]);
            unsigned short h1 = f2bf(xa[2 * p + 1]);
            Ah.u[p] = (unsigned int)h0 | ((unsigned int)h1 << 16);
            unsigned short l0 = f2bf(xa[2 * p] - bf2f(h0));
            unsigned short l1 = f2bf(xa[2 * p + 1] - bf2f(h1));
            Al.u[p] = (unsigned int)l0 | ((unsigned int)l1 << 16);
        }
        const unsigned short* wh = WhF + ((size_t)(s * 4) * 64 + lane) * 8;
        const unsigned short* wl = WlF + ((size_t)(s * 4) * 64 + lane) * 8;
#pragma unroll
        for (int cf = 0; cf < 4; cf++) {
            short8v bh = *(const short8v*)(wh + (size_t)cf * 64 * 8);
            short8v bl = *(const short8v*)(wl + (size_t)cf * 64 * 8);
            acc[cf] = __builtin_amdgcn_mfma_f32_16x16x32_bf16(Ah.v, bh, acc[cf], 0, 0, 0);
            acc[cf] = __builtin_amdgcn_mfma_f32_16x16x32_bf16(Al.v, bh, acc[cf], 0, 0, 0);
            acc[cf] = __builtin_amdgcn_mfma_f32_16x16x32_bf16(Ah.v, bl, acc[cf], 0, 0, 0);
        }
    }
    // D: row = wrow0 + 4*q + r, col = cf*16 + m  (HW-verified C/D mapping)
#pragma unroll
    for (int r = 0; r < 4; r++) {
        int row = wrow0 + q * 4 + r;
        if (row < n) {
            float dr = dis[row];
#pragma unroll
            for (int cf = 0; cf < 4; cf++) {
                HS[(size_t)row * FOUT + cf * 16 + m] = f2bf(acc[cf][r] * dr);
            }
        }
    }
}

// ---- aggregate: 2 nodes per wave, packed bf16x2 gathers ------------------
template <bool RELU>
__global__ __launch_bounds__(256) void aggregate(
    const unsigned int* __restrict__ hs32, const unsigned int* __restrict__ rowinfo,
    const int* __restrict__ col, const float* __restrict__ dis,
    const float* __restrict__ bias, float* __restrict__ out, int n) {
    const int wave = blockIdx.x * 4 + (threadIdx.x >> 6);
    const int lane = threadIdx.x & 63;
    const int half = lane >> 5;
    const int jj   = lane & 31;      // uint index within row (features 2jj,2jj+1)
    const int i = wave * 2 + half;
    if (i >= n) return;

    const unsigned int info = rowinfo[i];
    const int beg = (int)(info >> 8);
    const int end = beg + (int)(info & 255u);
    unsigned int su = hs32[(size_t)i * 32 + jj];  // self-loop term
    float a0 = bf2f(su & 0xFFFFu);
    float a1 = bf2f(su >> 16);

    const int hb = half << 5;
    for (int chunk = beg; chunk < end; chunk += 32) {
        int m = end - chunk;
        if (m > 32) m = 32;
        int c = (jj < m) ? col[chunk + jj] : 0;  // 32 cols per half-wave
        int q = 0;
        for (; q + 4 <= m; q += 4) {
            int s0 = __shfl(c, hb + q);
            int s1 = __shfl(c, hb + q + 1);
            int s2 = __shfl(c, hb + q + 2);
            int s3 = __shfl(c, hb + q + 3);
            unsigned int u0 = hs32[(size_t)s0 * 32 + jj];
            unsigned int u1 = hs32[(size_t)s1 * 32 + jj];
            unsigned int u2 = hs32[(size_t)s2 * 32 + jj];
            unsigned int u3 = hs32[(size_t)s3 * 32 + jj];
            a0 += bf2f(u0 & 0xFFFFu) + bf2f(u1 & 0xFFFFu) +
                  bf2f(u2 & 0xFFFFu) + bf2f(u3 & 0xFFFFu);
            a1 += bf2f(u0 >> 16) + bf2f(u1 >> 16) +
                  bf2f(u2 >> 16) + bf2f(u3 >> 16);
        }
        for (; q < m; q++) {
            int s = __shfl(c, hb + q);
            unsigned int u = hs32[(size_t)s * 32 + jj];
            a0 += bf2f(u & 0xFFFFu);
            a1 += bf2f(u >> 16);
        }
    }
    float d = dis[i];
    float2 bb = ((const float2*)bias)[jj];
    float v0 = d * a0 + bb.x;
    float v1 = d * a1 + bb.y;
    if (RELU) {
        v0 = fmaxf(v0, 0.0f);
        v1 = fmaxf(v1, 0.0f);
    }
    ((float2*)out)[(size_t)i * 32 + jj] = make_float2(v0, v1);
}

extern "C" void kernel_launch(void* const* d_in, const int* in_sizes, int n_in,
                              void* d_out, int out_size, void* d_ws, size_t ws_size,
                              hipStream_t stream) {
    const float* x  = (const float*)d_in[0];
    const int*   ei = (const int*)d_in[1];
    const float* W1 = (const float*)d_in[2];
    const float* b1 = (const float*)d_in[3];
    const float* W2 = (const float*)d_in[4];
    const float* b2 = (const float*)d_in[5];

    const int n = in_sizes[0] / 128;
    const int E = in_sizes[1] / 2;
    const int* srcp = ei;
    const int* dstp = ei + E;

    float* out = (float*)d_out;

    const int B = (n + BW - 1) / BW;
    const int nblk = (E + CHUNK - 1) / CHUNK;  // <= 512 required

    // workspace layout
    int*            cnt     = (int*)d_ws;                     // 512*MAXB
    int*            gcnt    = cnt + 512 * MAXB;               // MAXB
    unsigned int*   rowinfo = (unsigned int*)(gcnt + MAXB);   // n
    float*          dis     = (float*)(rowinfo + n);          // n
    int*            ebuf    = (int*)(dis + n);                // B*SLAB (becomes col)
    unsigned short* hs      = (unsigned short*)(ebuf + (size_t)B * SLAB);  // n*64 bf16
    unsigned short* whf1    = hs + (size_t)n * FOUT;          // NT1*8 (16B-aligned)
    unsigned short* wlf1    = whf1 + (size_t)NT1 * 8;
    unsigned short* whf2    = wlf1 + (size_t)NT1 * 8;
    unsigned short* wlf2    = whf2 + (size_t)NT2 * 8;

    // deterministic multisplit CSR build (no global atomics anywhere);
    // block 0 of edge_hist also pre-splits W1/W2 into bf16 hi/lo frag tables
    edge_hist<<<nblk, 512, 0, stream>>>(dstp, cnt, E, W1, W2,
                                        whf1, wlf1, whf2, wlf2);
    col_scan<<<B, 512, 0, stream>>>(cnt, nblk, gcnt);
    edge_place<<<nblk, 512, 0, stream>>>(srcp, dstp, cnt, ebuf, E);
    csr_build<<<B, 512, 0, stream>>>(ebuf, gcnt, rowinfo, dis, n);

    // layer 1: hs = bf16((x@W1)*dis) ; out = relu(dis*(hs_self + sum hs[nbr]) + b1)
    gemm_xw_mfma<128><<<(n + 63) / 64, 256, 0, stream>>>(x, whf1, wlf1, dis, hs, n);
    aggregate<true><<<(n + 7) / 8, 256, 0, stream>>>(
        (const unsigned int*)hs, rowinfo, ebuf, dis, b1, out, n);

    // layer 2: hs = bf16((out@W2)*dis) ; out = dis*(hs_self + sum hs[nbr]) + b2
    gemm_xw_mfma<64><<<(n + 63) / 64, 256, 0, stream>>>(out, whf2, wlf2, dis, hs, n);
    aggregate<false><<<(n + 7) / 8, 256, 0, stream>>>(
        (const unsigned int*)hs, rowinfo, ebuf, dis, b2, out, n);
}

// Round 2
// 229.929 us; speedup vs baseline: 1.0669x; 1.0085x over previous
//
#include <hip/hip_runtime.h>
#include <hip/hip_bf16.h>

// GCN 2-layer via CSR gather:
//   dis = rsqrt(indeg_by_dst + 1)
//   hs  = bf16( (x@W) * dis[row] )     (split-bf16 MFMA, fp32-accurate)
//   out[i] = act( dis[i] * (hs[i] + sum_{s in N(i)} hs[s]) + b )
// CSR build is a fully DETERMINISTIC two-pass multisplit (radix-sort style).
// GEMM is MFMA (16x16x32 bf16) with 2-term split of X and W:
//   x@W = xh@Wh + xh@Wl + xl@Wh  (+ xl@Wl ~ 2^-18, dropped)
// Aggregate is 8-lanes-per-node / uint4-per-lane: one wave serves 8 edges
// per load instruction (vs 2 with the old 32-lane/uint layout), 4 KB of
// gather bytes outstanding per wave with unroll-4 -> 4x latency hiding at
// identical byte traffic. Per-feature add order unchanged (bit-identical).

#define FOUT 64
#define BW 256        // nodes per bucket
#define BSH 8
#define MAXB 512      // >= ceil(n/BW), power of 2
#define CHUNK 4096    // edges per hist/place block; nblk = ceil(E/CHUNK) <= 512
#define SLAB 6144     // slab capacity per bucket (mean 4092 for E=1.6M,B=391)

#define NT1 1024      // W1 frag tasks: (128/32)*4*64
#define NT2 512       // W2 frag tasks: (64/32)*4*64

__device__ __forceinline__ float bf2f(unsigned int u16) {
    union { unsigned int i; float f; } c;
    c.i = u16 << 16;
    return c.f;
}
__device__ __forceinline__ unsigned short f2bf(float f) {
    union { float f; unsigned int i; } c;
    c.f = f;
    unsigned int i = c.i;
    return (unsigned short)((i + 0x7FFFu + ((i >> 16) & 1u)) >> 16);  // RN-even
}

typedef __attribute__((ext_vector_type(8))) short short8v;  // 8 bf16 = 4 VGPR
typedef __attribute__((ext_vector_type(4))) float f32x4;    // MFMA acc

// ---- W -> fragment-linear bf16 hi/lo split ------------------------------
// task = ((s*4 + cf)*64 + lane); element j of lane's B-frag is
// W[s*32 + (lane>>4)*8 + j][cf*16 + (lane&15)]  (same k-mapping as A-frags,
// so any internal k-permutation of the MFMA cancels between A and B).
__device__ __forceinline__ void conv_w_frag(const float* __restrict__ W,
                                            unsigned short* __restrict__ WhF,
                                            unsigned short* __restrict__ WlF,
                                            int task) {
    const int lane = task & 63;
    const int cf = (task >> 6) & 3;
    const int s = task >> 8;
    const int q = lane >> 4, m = lane & 15;
#pragma unroll
    for (int j = 0; j < 8; j++) {
        int k = s * 32 + q * 8 + j;
        float x = W[(size_t)k * 64 + cf * 16 + m];
        unsigned short h = f2bf(x);
        WhF[(size_t)task * 8 + j] = h;
        WlF[(size_t)task * 8 + j] = f2bf(x - bf2f(h));
    }
}

// ---- pass A: per-block bucket histogram -> cnt[blk][bucket] --------------
// block 0 additionally pre-splits W1/W2 into frag-linear bf16 hi/lo tables
// (1536 tasks / 512 threads = 3 iters, ~0.3 us, hidden under other blocks).
__global__ __launch_bounds__(512) void edge_hist(
    const int* __restrict__ dst, int* __restrict__ cnt, int E,
    const float* __restrict__ W1, const float* __restrict__ W2,
    unsigned short* __restrict__ whf1, unsigned short* __restrict__ wlf1,
    unsigned short* __restrict__ whf2, unsigned short* __restrict__ wlf2) {
    __shared__ int h[MAXB];
    const int blk = blockIdx.x, t = threadIdx.x;
    h[t] = 0;
    __syncthreads();
    const int e0 = blk * CHUNK;
#pragma unroll
    for (int k = 0; k < CHUNK / 512; k++) {
        int e = e0 + k * 512 + t;
        if (e < E) atomicAdd(&h[dst[e] >> BSH], 1);
    }
    if (blk == 0) {
        for (int task = t; task < NT1 + NT2; task += 512) {
            if (task < NT1) conv_w_frag(W1, whf1, wlf1, task);
            else            conv_w_frag(W2, whf2, wlf2, task - NT1);
        }
    }
    __syncthreads();
    cnt[blk * MAXB + t] = h[t];
}

// ---- pass B: per-bucket exclusive scan over blocks -> absolute bases -----
__global__ __launch_bounds__(512) void col_scan(int* __restrict__ cnt, int nblk,
                                                int* __restrict__ gcnt) {
    __shared__ int ts[512];
    const int b = blockIdx.x;  // bucket
    const int t = threadIdx.x;
    int v = (t < nblk) ? cnt[t * MAXB + b] : 0;
    ts[t] = v;
    __syncthreads();
    for (int off = 1; off < 512; off <<= 1) {
        int x = (t >= off) ? ts[t - off] : 0;
        __syncthreads();
        ts[t] += x;
        __syncthreads();
    }
    if (t < nblk) cnt[t * MAXB + b] = b * SLAB + ts[t] - v;  // abs base
    if (t == 511) gcnt[b] = ts[511];                          // bucket total
}

// ---- pass C: placement at precomputed bases (no global atomics) ----------
__global__ __launch_bounds__(512) void edge_place(
    const int* __restrict__ src, const int* __restrict__ dst,
    const int* __restrict__ cnt, int* __restrict__ ebuf, int E) {
    __shared__ int lbase[MAXB];
    __shared__ int cur[MAXB];
    const int blk = blockIdx.x, t = threadIdx.x;
    lbase[t] = cnt[blk * MAXB + t];
    cur[t] = 0;
    __syncthreads();
    const int e0 = blk * CHUNK;
#pragma unroll
    for (int k = 0; k < CHUNK / 512; k++) {
        int e = e0 + k * 512 + t;
        if (e < E) {
            int d = dst[e];
            int b = d >> BSH;
            int r = atomicAdd(&cur[b], 1);  // LDS only
            ebuf[lbase[b] + r] = src[e] | ((d & (BW - 1)) << 17);  // src < 2^17
        }
    }
}

// ---- per-bucket finalize: degree/scan/dis/rowinfo, rank ebuf IN PLACE ----
__global__ __launch_bounds__(512) void csr_build(
    int* __restrict__ ebuf, const int* __restrict__ gcnt,
    unsigned int* __restrict__ rowinfo, float* __restrict__ dis, int n) {
    __shared__ int ldeg[BW];
    __shared__ int lscan[BW];
    const int b = blockIdx.x, t = threadIdx.x;
    const int node0 = b << BSH;
    const int nn = min(BW, n - node0);
    const int ebeg = b * SLAB;
    const int cnt = gcnt[b];

    // stage this bucket's edge words in registers (SLAB/512 = 12 max)
    int w[SLAB / 512];
#pragma unroll
    for (int k = 0; k < SLAB / 512; k++) {
        int idx = t + k * 512;
        w[k] = (idx < cnt) ? ebuf[ebeg + idx] : -1;
    }
    if (t < BW) ldeg[t] = 0;
    __syncthreads();
#pragma unroll
    for (int k = 0; k < SLAB / 512; k++)
        if (w[k] >= 0) atomicAdd(&ldeg[w[k] >> 17], 1);
    __syncthreads();
    int v = 0;
    if (t < BW) {
        v = ldeg[t];
        lscan[t] = v;
    }
    __syncthreads();
    for (int off = 1; off < BW; off <<= 1) {
        int x = 0;
        if (t < BW && t >= off) x = lscan[t - off];
        __syncthreads();
        if (t < BW) lscan[t] += x;
        __syncthreads();
    }
    if (t < nn) {
        int ex = lscan[t] - v;  // exclusive prefix within bucket
        rowinfo[node0 + t] = ((unsigned int)(ebeg + ex) << 8) | (unsigned int)v;
        dis[node0 + t] = rsqrtf((float)v + 1.0f);  // +1 self-loop
    }
    __syncthreads();
    if (t < BW) ldeg[t] = lscan[t] - v;  // reuse as write cursor
    __syncthreads();
    // all words are register-staged (barrier above) => in-place rewrite safe
#pragma unroll
    for (int k = 0; k < SLAB / 512; k++)
        if (w[k] >= 0) {
            int r = atomicAdd(&ldeg[w[k] >> 17], 1);
            ebuf[ebeg + r] = w[k] & 0x1FFFF;  // ebuf becomes col
        }
}

// ---- GEMM: HS[n x 64] = bf16( (X[n x K] @ W[K x 64]) * dis[row] ) --------
// Split-bf16 MFMA: 4 waves/block, wave owns 16 rows x 64 cols (4 col-frags,
// 16x16x32 bf16). A-frags read straight from global (each X elem exactly
// once per kernel), split to hi/lo in-register; B-frags from the
// frag-linear tables (L1/L2-resident, 16B/lane coalesced). No LDS, no
// __syncthreads. 3 MFMA per (kstep, col-frag): AhBh + AlBh + AhBl.
template <int K>
__global__ __launch_bounds__(256) void gemm_xw_mfma(
    const float* __restrict__ X,
    const unsigned short* __restrict__ WhF,
    const unsigned short* __restrict__ WlF,
    const float* __restrict__ dis,
    unsigned short* __restrict__ HS, int n) {
    const int lane = threadIdx.x & 63;
    const int wv = threadIdx.x >> 6;
    const int wrow0 = blockIdx.x * 64 + wv * 16;
    const int m = lane & 15;   // A: row-in-tile / B: col-in-frag / D: col
    const int q = lane >> 4;   // k-group (A/B), row-quad (D)

    f32x4 acc[4];
#pragma unroll
    for (int cf = 0; cf < 4; cf++) acc[cf] = (f32x4)0.f;

    const int arow = wrow0 + m;
    const bool rok = (arow < n);
    const float* xp = X + (size_t)arow * K + q * 8;

#pragma unroll
    for (int s = 0; s < K / 32; s++) {
        float4 v0, v1;
        if (rok) {
            v0 = *(const float4*)(xp + s * 32);
            v1 = *(const float4*)(xp + s * 32 + 4);
        } else {
            v0 = make_float4(0.f, 0.f, 0.f, 0.f);
            v1 = v0;
        }
        const float xa[8] = {v0.x, v0.y, v0.z, v0.w, v1.x, v1.y, v1.z, v1.w};
        union { unsigned int u[4]; short8v v; } Ah, Al;
#pragma unroll
        for (int p = 0; p < 4; p++) {
            unsigned short h0 = f2bf(xa[2 * p]);
            unsigned short h1 = f2bf(xa[2 * p + 1]);
            Ah.u[p] = (unsigned int)h0 | ((unsigned int)h1 << 16);
            unsigned short l0 = f2bf(xa[2 * p] - bf2f(h0));
            unsigned short l1 = f2bf(xa[2 * p + 1] - bf2f(h1));
            Al.u[p] = (unsigned int)l0 | ((unsigned int)l1 << 16);
        }
        const unsigned short* wh = WhF + ((size_t)(s * 4) * 64 + lane) * 8;
        const unsigned short* wl = WlF + ((size_t)(s * 4) * 64 + lane) * 8;
#pragma unroll
        for (int cf = 0; cf < 4; cf++) {
            short8v bh = *(const short8v*)(wh + (size_t)cf * 64 * 8);
            short8v bl = *(const short8v*)(wl + (size_t)cf * 64 * 8);
            acc[cf] = __builtin_amdgcn_mfma_f32_16x16x32_bf16(Ah.v, bh, acc[cf], 0, 0, 0);
            acc[cf] = __builtin_amdgcn_mfma_f32_16x16x32_bf16(Al.v, bh, acc[cf], 0, 0, 0);
            acc[cf] = __builtin_amdgcn_mfma_f32_16x16x32_bf16(Ah.v, bl, acc[cf], 0, 0, 0);
        }
    }
    // D: row = wrow0 + 4*q + r, col = cf*16 + m  (HW-verified C/D mapping)
#pragma unroll
    for (int r = 0; r < 4; r++) {
        int row = wrow0 + q * 4 + r;
        if (row < n) {
            float dr = dis[row];
#pragma unroll
            for (int cf = 0; cf < 4; cf++) {
                HS[(size_t)row * FOUT + cf * 16 + m] = f2bf(acc[cf][r] * dr);
            }
        }
    }
}

// ---- aggregate: 8 nodes per wave, uint4 (8 feats) per lane ---------------
// Each 8-lane group owns one node; a single wave load instruction gathers
// 8 full 128B rows (one per group). unroll-4 => 4KB outstanding per wave.
// Per-feature summation order identical to the 32-lane version.
__device__ __forceinline__ void acc8(const uint4 u, float* a) {
    a[0] += bf2f(u.x & 0xFFFFu); a[1] += bf2f(u.x >> 16);
    a[2] += bf2f(u.y & 0xFFFFu); a[3] += bf2f(u.y >> 16);
    a[4] += bf2f(u.z & 0xFFFFu); a[5] += bf2f(u.z >> 16);
    a[6] += bf2f(u.w & 0xFFFFu); a[7] += bf2f(u.w >> 16);
}

template <bool RELU>
__global__ __launch_bounds__(256) void aggregate(
    const uint4* __restrict__ hsv, const unsigned int* __restrict__ rowinfo,
    const int* __restrict__ col, const float* __restrict__ dis,
    const float* __restrict__ bias, float* __restrict__ out, int n) {
    const int wave = blockIdx.x * 4 + (threadIdx.x >> 6);
    const int lane = threadIdx.x & 63;
    const int g  = lane >> 3;       // group 0..7 -> node
    const int jj = lane & 7;        // uint4 index within row (feats 8jj..8jj+7)
    const int i = wave * 8 + g;
    if (i >= n) return;

    const unsigned int info = rowinfo[i];
    const int beg = (int)(info >> 8);
    const int end = beg + (int)(info & 255u);

    float a[8];
    acc8(hsv[(size_t)i * 8 + jj], a);  // wrong: acc8 adds; init below instead
    // (re-init properly: self-loop term is the first contribution)
    {
        uint4 su = hsv[(size_t)i * 8 + jj];
        a[0] = bf2f(su.x & 0xFFFFu); a[1] = bf2f(su.x >> 16);
        a[2] = bf2f(su.y & 0xFFFFu); a[3] = bf2f(su.y >> 16);
        a[4] = bf2f(su.z & 0xFFFFu); a[5] = bf2f(su.z >> 16);
        a[6] = bf2f(su.w & 0xFFFFu); a[7] = bf2f(su.w >> 16);
    }

    const int gb = g << 3;
    for (int chunk = beg; chunk < end; chunk += 8) {
        int m = end - chunk;
        if (m > 8) m = 8;
        int c = (chunk + jj < end) ? col[chunk + jj] : 0;  // 8 cols per group
        int q = 0;
        for (; q + 4 <= m; q += 4) {
            int s0 = __shfl(c, gb + q);
            int s1 = __shfl(c, gb + q + 1);
            int s2 = __shfl(c, gb + q + 2);
            int s3 = __shfl(c, gb + q + 3);
            uint4 u0 = hsv[(size_t)s0 * 8 + jj];
            uint4 u1 = hsv[(size_t)s1 * 8 + jj];
            uint4 u2 = hsv[(size_t)s2 * 8 + jj];
            uint4 u3 = hsv[(size_t)s3 * 8 + jj];
            acc8(u0, a);
            acc8(u1, a);
            acc8(u2, a);
            acc8(u3, a);
        }
        for (; q < m; q++) {
            int s = __shfl(c, gb + q);
            acc8(hsv[(size_t)s * 8 + jj], a);
        }
    }
    float d = dis[i];
    const float4* b4 = (const float4*)bias;
    float4 bb0 = b4[jj * 2];
    float4 bb1 = b4[jj * 2 + 1];
    float4 o0, o1;
    o0.x = d * a[0] + bb0.x; o0.y = d * a[1] + bb0.y;
    o0.z = d * a[2] + bb0.z; o0.w = d * a[3] + bb0.w;
    o1.x = d * a[4] + bb1.x; o1.y = d * a[5] + bb1.y;
    o1.z = d * a[6] + bb1.z; o1.w = d * a[7] + bb1.w;
    if (RELU) {
        o0.x = fmaxf(o0.x, 0.f); o0.y = fmaxf(o0.y, 0.f);
        o0.z = fmaxf(o0.z, 0.f); o0.w = fmaxf(o0.w, 0.f);
        o1.x = fmaxf(o1.x, 0.f); o1.y = fmaxf(o1.y, 0.f);
        o1.z = fmaxf(o1.z, 0.f); o1.w = fmaxf(o1.w, 0.f);
    }
    float4* orow = (float4*)out + (size_t)i * 16 + jj * 2;
    orow[0] = o0;
    orow[1] = o1;
}

extern "C" void kernel_launch(void* const* d_in, const int* in_sizes, int n_in,
                              void* d_out, int out_size, void* d_ws, size_t ws_size,
                              hipStream_t stream) {
    const float* x  = (const float*)d_in[0];
    const int*   ei = (const int*)d_in[1];
    const float* W1 = (const float*)d_in[2];
    const float* b1 = (const float*)d_in[3];
    const float* W2 = (const float*)d_in[4];
    const float* b2 = (const float*)d_in[5];

    const int n = in_sizes[0] / 128;
    const int E = in_sizes[1] / 2;
    const int* srcp = ei;
    const int* dstp = ei + E;

    float* out = (float*)d_out;

    const int B = (n + BW - 1) / BW;
    const int nblk = (E + CHUNK - 1) / CHUNK;  // <= 512 required

    // workspace layout
    int*            cnt     = (int*)d_ws;                     // 512*MAXB
    int*            gcnt    = cnt + 512 * MAXB;               // MAXB
    unsigned int*   rowinfo = (unsigned int*)(gcnt + MAXB);   // n
    float*          dis     = (float*)(rowinfo + n);          // n
    int*            ebuf    = (int*)(dis + n);                // B*SLAB (becomes col)
    unsigned short* hs      = (unsigned short*)(ebuf + (size_t)B * SLAB);  // n*64 bf16
    unsigned short* whf1    = hs + (size_t)n * FOUT;          // NT1*8 (16B-aligned)
    unsigned short* wlf1    = whf1 + (size_t)NT1 * 8;
    unsigned short* whf2    = wlf1 + (size_t)NT1 * 8;
    unsigned short* wlf2    = whf2 + (size_t)NT2 * 8;

    // deterministic multisplit CSR build (no global atomics anywhere);
    // block 0 of edge_hist also pre-splits W1/W2 into bf16 hi/lo frag tables
    edge_hist<<<nblk, 512, 0, stream>>>(dstp, cnt, E, W1, W2,
                                        whf1, wlf1, whf2, wlf2);
    col_scan<<<B, 512, 0, stream>>>(cnt, nblk, gcnt);
    edge_place<<<nblk, 512, 0, stream>>>(srcp, dstp, cnt, ebuf, E);
    csr_build<<<B, 512, 0, stream>>>(ebuf, gcnt, rowinfo, dis, n);

    // layer 1: hs = bf16((x@W1)*dis) ; out = relu(dis*(hs_self + sum hs[nbr]) + b1)
    gemm_xw_mfma<128><<<(n + 63) / 64, 256, 0, stream>>>(x, whf1, wlf1, dis, hs, n);
    aggregate<true><<<(n + 31) / 32, 256, 0, stream>>>(
        (const uint4*)hs, rowinfo, ebuf, dis, b1, out, n);

    // layer 2: hs = bf16((out@W2)*dis) ; out = dis*(hs_self + sum hs[nbr]) + b2
    gemm_xw_mfma<64><<<(n + 63) / 64, 256, 0, stream>>>(out, whf2, wlf2, dis, hs, n);
    aggregate<false><<<(n + 31) / 32, 256, 0, stream>>>(
        (const uint4*)hs, rowinfo, ebuf, dis, b2, out, n);
}

// Round 3
// 223.960 us; speedup vs baseline: 1.0954x; 1.0267x over previous
//
#include <hip/hip_runtime.h>
#include <hip/hip_bf16.h>

// GCN 2-layer via CSR gather:
//   dis = rsqrt(indeg_by_dst + 1)
//   hs  = bf16( (x@W) * dis[row] )     (split-bf16 MFMA, fp32-accurate)
//   out[i] = act( dis[i] * (hs[i] + sum_{s in N(i)} hs[s]) + b )
// CSR build is a fully DETERMINISTIC two-pass multisplit (radix-sort style).
// GEMM is MFMA (16x16x32 bf16) with 2-term split of X and W:
//   x@W = xh@Wh + xh@Wl + xl@Wh  (+ xl@Wl ~ 2^-18, dropped)
// R2 fusions (dispatches 8 -> 6, out1 never hits global memory):
//   csr_gemm  = csr_build + gemm1   (bucket b's dis rows == gemm block rows;
//                                    dis stays in LDS)
//   agg_gemm  = aggregate1 + gemm2  (out1 rows are block-local: aggregate
//                                    writes relu'd rows to LDS, barrier,
//                                    split-MFMA from LDS -> hs2. Saves the
//                                    25.6MB x2 out1 round-trip + a boundary.
//                                    MFMA order identical to old gemm2 ->
//                                    bit-identical hs2.)

#define FOUT 64
#define BW 256        // nodes per bucket
#define BSH 8
#define MAXB 512      // >= ceil(n/BW), power of 2
#define CHUNK 4096    // edges per hist/place block; nblk = ceil(E/CHUNK) <= 512
#define SLAB 6144     // slab capacity per bucket (mean 4092 for E=1.6M,B=391)

#define NT1 1024      // W1 frag tasks: (128/32)*4*64
#define NT2 512       // W2 frag tasks: (64/32)*4*64

__device__ __forceinline__ float bf2f(unsigned int u16) {
    union { unsigned int i; float f; } c;
    c.i = u16 << 16;
    return c.f;
}
__device__ __forceinline__ unsigned short f2bf(float f) {
    union { float f; unsigned int i; } c;
    c.f = f;
    unsigned int i = c.i;
    return (unsigned short)((i + 0x7FFFu + ((i >> 16) & 1u)) >> 16);  // RN-even
}

typedef __attribute__((ext_vector_type(8))) short short8v;  // 8 bf16 = 4 VGPR
typedef __attribute__((ext_vector_type(4))) float f32x4;    // MFMA acc

// ---- split fp32x8 -> bf16 hi/lo A-fragments ------------------------------
__device__ __forceinline__ void split_frag(const float* xa, short8v* Ah, short8v* Al) {
    union { unsigned int u[4]; short8v v; } H, L;
#pragma unroll
    for (int p = 0; p < 4; p++) {
        unsigned short h0 = f2bf(xa[2 * p]);
        unsigned short h1 = f2bf(xa[2 * p + 1]);
        H.u[p] = (unsigned int)h0 | ((unsigned int)h1 << 16);
        unsigned short l0 = f2bf(xa[2 * p] - bf2f(h0));
        unsigned short l1 = f2bf(xa[2 * p + 1] - bf2f(h1));
        L.u[p] = (unsigned int)l0 | ((unsigned int)l1 << 16);
    }
    *Ah = H.v;
    *Al = L.v;
}

// ---- W -> fragment-linear bf16 hi/lo split ------------------------------
// task = ((s*4 + cf)*64 + lane); element j of lane's B-frag is
// W[s*32 + (lane>>4)*8 + j][cf*16 + (lane&15)]  (same k-mapping as A-frags,
// so any internal k-permutation of the MFMA cancels between A and B).
__device__ __forceinline__ void conv_w_frag(const float* __restrict__ W,
                                            unsigned short* __restrict__ WhF,
                                            unsigned short* __restrict__ WlF,
                                            int task) {
    const int lane = task & 63;
    const int cf = (task >> 6) & 3;
    const int s = task >> 8;
    const int q = lane >> 4, m = lane & 15;
#pragma unroll
    for (int j = 0; j < 8; j++) {
        int k = s * 32 + q * 8 + j;
        float x = W[(size_t)k * 64 + cf * 16 + m];
        unsigned short h = f2bf(x);
        WhF[(size_t)task * 8 + j] = h;
        WlF[(size_t)task * 8 + j] = f2bf(x - bf2f(h));
    }
}

// ---- pass A: per-block bucket histogram -> cnt[blk][bucket] --------------
// block 0 additionally pre-splits W1/W2 into frag-linear bf16 hi/lo tables.
__global__ __launch_bounds__(512) void edge_hist(
    const int* __restrict__ dst, int* __restrict__ cnt, int E,
    const float* __restrict__ W1, const float* __restrict__ W2,
    unsigned short* __restrict__ whf1, unsigned short* __restrict__ wlf1,
    unsigned short* __restrict__ whf2, unsigned short* __restrict__ wlf2) {
    __shared__ int h[MAXB];
    const int blk = blockIdx.x, t = threadIdx.x;
    h[t] = 0;
    __syncthreads();
    const int e0 = blk * CHUNK;
#pragma unroll
    for (int k = 0; k < CHUNK / 512; k++) {
        int e = e0 + k * 512 + t;
        if (e < E) atomicAdd(&h[dst[e] >> BSH], 1);
    }
    if (blk == 0) {
        for (int task = t; task < NT1 + NT2; task += 512) {
            if (task < NT1) conv_w_frag(W1, whf1, wlf1, task);
            else            conv_w_frag(W2, whf2, wlf2, task - NT1);
        }
    }
    __syncthreads();
    cnt[blk * MAXB + t] = h[t];
}

// ---- pass B: per-bucket exclusive scan over blocks -> absolute bases -----
__global__ __launch_bounds__(512) void col_scan(int* __restrict__ cnt, int nblk,
                                                int* __restrict__ gcnt) {
    __shared__ int ts[512];
    const int b = blockIdx.x;  // bucket
    const int t = threadIdx.x;
    int v = (t < nblk) ? cnt[t * MAXB + b] : 0;
    ts[t] = v;
    __syncthreads();
    for (int off = 1; off < 512; off <<= 1) {
        int x = (t >= off) ? ts[t - off] : 0;
        __syncthreads();
        ts[t] += x;
        __syncthreads();
    }
    if (t < nblk) cnt[t * MAXB + b] = b * SLAB + ts[t] - v;  // abs base
    if (t == 511) gcnt[b] = ts[511];                          // bucket total
}

// ---- pass C: placement at precomputed bases (no global atomics) ----------
__global__ __launch_bounds__(512) void edge_place(
    const int* __restrict__ src, const int* __restrict__ dst,
    const int* __restrict__ cnt, int* __restrict__ ebuf, int E) {
    __shared__ int lbase[MAXB];
    __shared__ int cur[MAXB];
    const int blk = blockIdx.x, t = threadIdx.x;
    lbase[t] = cnt[blk * MAXB + t];
    cur[t] = 0;
    __syncthreads();
    const int e0 = blk * CHUNK;
#pragma unroll
    for (int k = 0; k < CHUNK / 512; k++) {
        int e = e0 + k * 512 + t;
        if (e < E) {
            int d = dst[e];
            int b = d >> BSH;
            int r = atomicAdd(&cur[b], 1);  // LDS only
            ebuf[lbase[b] + r] = src[e] | ((d & (BW - 1)) << 17);  // src < 2^17
        }
    }
}

// ---- fused: per-bucket CSR finalize + gemm1 for the bucket's 256 rows ----
// CSR part identical to old csr_build (ranks ebuf in place, emits rowinfo,
// dis). dis additionally kept in LDS; gemm1 (split-bf16 MFMA, 8 waves x
// 2 tiles of 16 rows) follows in the same block.
template <int K>
__global__ __launch_bounds__(512) void csr_gemm(
    int* __restrict__ ebuf, const int* __restrict__ gcnt,
    unsigned int* __restrict__ rowinfo, float* __restrict__ dis, int n,
    const float* __restrict__ X, const unsigned short* __restrict__ WhF,
    const unsigned short* __restrict__ WlF, unsigned short* __restrict__ HS) {
    __shared__ int ldeg[BW];
    __shared__ int lscan[BW];
    __shared__ float sdis[BW];
    const int b = blockIdx.x, t = threadIdx.x;
    const int node0 = b << BSH;
    const int nn = min(BW, n - node0);
    const int ebeg = b * SLAB;
    const int cnt = gcnt[b];

    // stage this bucket's edge words in registers (SLAB/512 = 12 max)
    int w[SLAB / 512];
#pragma unroll
    for (int k = 0; k < SLAB / 512; k++) {
        int idx = t + k * 512;
        w[k] = (idx < cnt) ? ebuf[ebeg + idx] : -1;
    }
    if (t < BW) ldeg[t] = 0;
    __syncthreads();
#pragma unroll
    for (int k = 0; k < SLAB / 512; k++)
        if (w[k] >= 0) atomicAdd(&ldeg[w[k] >> 17], 1);
    __syncthreads();
    int v = 0;
    if (t < BW) {
        v = ldeg[t];
        lscan[t] = v;
    }
    __syncthreads();
    for (int off = 1; off < BW; off <<= 1) {
        int x = 0;
        if (t < BW && t >= off) x = lscan[t - off];
        __syncthreads();
        if (t < BW) lscan[t] += x;
        __syncthreads();
    }
    if (t < nn) {
        int ex = lscan[t] - v;  // exclusive prefix within bucket
        rowinfo[node0 + t] = ((unsigned int)(ebeg + ex) << 8) | (unsigned int)v;
        float dv = rsqrtf((float)v + 1.0f);  // +1 self-loop
        dis[node0 + t] = dv;
        sdis[t] = dv;
    } else if (t < BW) {
        sdis[t] = 0.f;
    }
    __syncthreads();
    if (t < BW) ldeg[t] = lscan[t] - v;  // reuse as write cursor
    __syncthreads();
    // all words are register-staged (barrier above) => in-place rewrite safe
#pragma unroll
    for (int k = 0; k < SLAB / 512; k++)
        if (w[k] >= 0) {
            int r = atomicAdd(&ldeg[w[k] >> 17], 1);
            ebuf[ebeg + r] = w[k] & 0x1FFFF;  // ebuf becomes col
        }

    // ---- gemm1 for rows [node0, node0+256) -- sdis valid (barrier above),
    // gemm touches neither ebuf nor the csr LDS arrays, so no extra barrier.
    const int lane = t & 63;
    const int wvv = t >> 6;                 // 8 waves
    const int m = lane & 15;                // A row-in-tile / D col
    const int q = lane >> 4;                // A k-group / D row-quad
#pragma unroll 1
    for (int t2 = 0; t2 < 2; t2++) {
        const int tile = wvv * 2 + t2;      // 0..15
        const int wrow0 = node0 + tile * 16;
        f32x4 acc[4];
#pragma unroll
        for (int cf = 0; cf < 4; cf++) acc[cf] = (f32x4)0.f;

        const int arow = wrow0 + m;
        const bool rok = (arow < n);
        const float* xp = X + (size_t)arow * K + q * 8;
#pragma unroll
        for (int s = 0; s < K / 32; s++) {
            float4 v0, v1;
            if (rok) {
                v0 = *(const float4*)(xp + s * 32);
                v1 = *(const float4*)(xp + s * 32 + 4);
            } else {
                v0 = make_float4(0.f, 0.f, 0.f, 0.f);
                v1 = v0;
            }
            const float xa[8] = {v0.x, v0.y, v0.z, v0.w, v1.x, v1.y, v1.z, v1.w};
            short8v Ah, Al;
            split_frag(xa, &Ah, &Al);
            const unsigned short* wh = WhF + ((size_t)(s * 4) * 64 + lane) * 8;
            const unsigned short* wl = WlF + ((size_t)(s * 4) * 64 + lane) * 8;
#pragma unroll
            for (int cf = 0; cf < 4; cf++) {
                short8v bh = *(const short8v*)(wh + (size_t)cf * 64 * 8);
                short8v bl = *(const short8v*)(wl + (size_t)cf * 64 * 8);
                acc[cf] = __builtin_amdgcn_mfma_f32_16x16x32_bf16(Ah, bh, acc[cf], 0, 0, 0);
                acc[cf] = __builtin_amdgcn_mfma_f32_16x16x32_bf16(Al, bh, acc[cf], 0, 0, 0);
                acc[cf] = __builtin_amdgcn_mfma_f32_16x16x32_bf16(Ah, bl, acc[cf], 0, 0, 0);
            }
        }
        // D: row = wrow0 + 4*q + r, col = cf*16 + m
#pragma unroll
        for (int r = 0; r < 4; r++) {
            int row = wrow0 + q * 4 + r;
            if (row < n) {
                float dr = sdis[tile * 16 + q * 4 + r];
#pragma unroll
                for (int cf = 0; cf < 4; cf++) {
                    HS[(size_t)row * FOUT + cf * 16 + m] = f2bf(acc[cf][r] * dr);
                }
            }
        }
    }
}

// ---- aggregate helpers ---------------------------------------------------
__device__ __forceinline__ void acc8(const uint4 u, float* a) {
    a[0] += bf2f(u.x & 0xFFFFu); a[1] += bf2f(u.x >> 16);
    a[2] += bf2f(u.y & 0xFFFFu); a[3] += bf2f(u.y >> 16);
    a[4] += bf2f(u.z & 0xFFFFu); a[5] += bf2f(u.z >> 16);
    a[6] += bf2f(u.w & 0xFFFFu); a[7] += bf2f(u.w >> 16);
}

// ---- fused: aggregate1 (+relu) -> LDS -> gemm2 -> hs2 --------------------
// 256 threads = 4 waves = 32 nodes (8-lane group per node, uint4 per lane).
// out1 rows live only in LDS (stride 68 floats: 16B-aligned, 2-way bank
// aliasing = free). MFMA phase: wave wv handles tile (wv>>1), col-half
// (wv&1): 16 rows x 32 cols, K=64. MFMA sequence per accumulator identical
// to the old standalone gemm2 -> bit-identical hs2.
#define OSTR 68
__global__ __launch_bounds__(256) void agg_gemm(
    const uint4* __restrict__ hsv, const unsigned int* __restrict__ rowinfo,
    const int* __restrict__ col, const float* __restrict__ dis,
    const float* __restrict__ bias,
    const unsigned short* __restrict__ WhF2, const unsigned short* __restrict__ WlF2,
    unsigned short* __restrict__ HS2, int n) {
    __shared__ float so[32 * OSTR];  // 8704 B
    const int tid = threadIdx.x;
    const int wv = tid >> 6;
    const int lane = tid & 63;
    const int g = lane >> 3;        // group 0..7 -> node
    const int jj = lane & 7;        // uint4 index within row (feats 8jj..8jj+7)
    const int lrow = wv * 8 + g;    // 0..31
    const int i = blockIdx.x * 32 + lrow;

    float o[8];
#pragma unroll
    for (int p = 0; p < 8; p++) o[p] = 0.f;

    if (i < n) {
        const unsigned int info = rowinfo[i];
        const int beg = (int)(info >> 8);
        const int end = beg + (int)(info & 255u);

        float a[8];
        {
            uint4 su = hsv[(size_t)i * 8 + jj];  // self-loop term
            a[0] = bf2f(su.x & 0xFFFFu); a[1] = bf2f(su.x >> 16);
            a[2] = bf2f(su.y & 0xFFFFu); a[3] = bf2f(su.y >> 16);
            a[4] = bf2f(su.z & 0xFFFFu); a[5] = bf2f(su.z >> 16);
            a[6] = bf2f(su.w & 0xFFFFu); a[7] = bf2f(su.w >> 16);
        }
        const int gb = g << 3;
        for (int chunk = beg; chunk < end; chunk += 8) {
            int m = end - chunk;
            if (m > 8) m = 8;
            int c = (chunk + jj < end) ? col[chunk + jj] : 0;
            int q = 0;
            for (; q + 4 <= m; q += 4) {
                int s0 = __shfl(c, gb + q);
                int s1 = __shfl(c, gb + q + 1);
                int s2 = __shfl(c, gb + q + 2);
                int s3 = __shfl(c, gb + q + 3);
                uint4 u0 = hsv[(size_t)s0 * 8 + jj];
                uint4 u1 = hsv[(size_t)s1 * 8 + jj];
                uint4 u2 = hsv[(size_t)s2 * 8 + jj];
                uint4 u3 = hsv[(size_t)s3 * 8 + jj];
                acc8(u0, a);
                acc8(u1, a);
                acc8(u2, a);
                acc8(u3, a);
            }
            for (; q < m; q++) {
                int s = __shfl(c, gb + q);
                acc8(hsv[(size_t)s * 8 + jj], a);
            }
        }
        float d = dis[i];
        const float4* b4 = (const float4*)bias;
        float4 bb0 = b4[jj * 2];
        float4 bb1 = b4[jj * 2 + 1];
        o[0] = fmaxf(d * a[0] + bb0.x, 0.f);
        o[1] = fmaxf(d * a[1] + bb0.y, 0.f);
        o[2] = fmaxf(d * a[2] + bb0.z, 0.f);
        o[3] = fmaxf(d * a[3] + bb0.w, 0.f);
        o[4] = fmaxf(d * a[4] + bb1.x, 0.f);
        o[5] = fmaxf(d * a[5] + bb1.y, 0.f);
        o[6] = fmaxf(d * a[6] + bb1.z, 0.f);
        o[7] = fmaxf(d * a[7] + bb1.w, 0.f);
    }
    {
        float* sp = &so[lrow * OSTR + jj * 8];
        *(float4*)sp = make_float4(o[0], o[1], o[2], o[3]);
        *(float4*)(sp + 4) = make_float4(o[4], o[5], o[6], o[7]);
    }
    __syncthreads();

    // ---- gemm2 from LDS: hs2 = bf16((out1 @ W2) * dis) ------------------
    const int tile = wv >> 1;       // 0..1 (16-row tile)
    const int ch = wv & 1;          // col half: cf in {2ch, 2ch+1}
    const int m = lane & 15;
    const int q = lane >> 4;
    f32x4 acc[2];
    acc[0] = (f32x4)0.f;
    acc[1] = (f32x4)0.f;
#pragma unroll
    for (int s = 0; s < 2; s++) {
        const float* ap = &so[(tile * 16 + m) * OSTR + s * 32 + q * 8];
        float4 v0 = *(const float4*)ap;
        float4 v1 = *(const float4*)(ap + 4);
        const float xa[8] = {v0.x, v0.y, v0.z, v0.w, v1.x, v1.y, v1.z, v1.w};
        short8v Ah, Al;
        split_frag(xa, &Ah, &Al);
#pragma unroll
        for (int c = 0; c < 2; c++) {
            int cf = ch * 2 + c;
            const unsigned short* wh = WhF2 + ((size_t)(s * 4 + cf) * 64 + lane) * 8;
            const unsigned short* wl = WlF2 + ((size_t)(s * 4 + cf) * 64 + lane) * 8;
            short8v bh = *(const short8v*)wh;
            short8v bl = *(const short8v*)wl;
            acc[c] = __builtin_amdgcn_mfma_f32_16x16x32_bf16(Ah, bh, acc[c], 0, 0, 0);
            acc[c] = __builtin_amdgcn_mfma_f32_16x16x32_bf16(Al, bh, acc[c], 0, 0, 0);
            acc[c] = __builtin_amdgcn_mfma_f32_16x16x32_bf16(Ah, bl, acc[c], 0, 0, 0);
        }
    }
#pragma unroll
    for (int r = 0; r < 4; r++) {
        int lr = tile * 16 + q * 4 + r;
        int i2 = blockIdx.x * 32 + lr;
        if (i2 < n) {
            float dr = dis[i2];
#pragma unroll
            for (int c = 0; c < 2; c++) {
                HS2[(size_t)i2 * FOUT + (ch * 2 + c) * 16 + m] = f2bf(acc[c][r] * dr);
            }
        }
    }
}

// ---- aggregate (layer 2): 8 nodes per wave, uint4 per lane ---------------
template <bool RELU>
__global__ __launch_bounds__(256) void aggregate(
    const uint4* __restrict__ hsv, const unsigned int* __restrict__ rowinfo,
    const int* __restrict__ col, const float* __restrict__ dis,
    const float* __restrict__ bias, float* __restrict__ out, int n) {
    const int wave = blockIdx.x * 4 + (threadIdx.x >> 6);
    const int lane = threadIdx.x & 63;
    const int g  = lane >> 3;
    const int jj = lane & 7;
    const int i = wave * 8 + g;
    if (i >= n) return;

    const unsigned int info = rowinfo[i];
    const int beg = (int)(info >> 8);
    const int end = beg + (int)(info & 255u);

    float a[8];
    {
        uint4 su = hsv[(size_t)i * 8 + jj];
        a[0] = bf2f(su.x & 0xFFFFu); a[1] = bf2f(su.x >> 16);
        a[2] = bf2f(su.y & 0xFFFFu); a[3] = bf2f(su.y >> 16);
        a[4] = bf2f(su.z & 0xFFFFu); a[5] = bf2f(su.z >> 16);
        a[6] = bf2f(su.w & 0xFFFFu); a[7] = bf2f(su.w >> 16);
    }

    const int gb = g << 3;
    for (int chunk = beg; chunk < end; chunk += 8) {
        int m = end - chunk;
        if (m > 8) m = 8;
        int c = (chunk + jj < end) ? col[chunk + jj] : 0;
        int q = 0;
        for (; q + 4 <= m; q += 4) {
            int s0 = __shfl(c, gb + q);
            int s1 = __shfl(c, gb + q + 1);
            int s2 = __shfl(c, gb + q + 2);
            int s3 = __shfl(c, gb + q + 3);
            uint4 u0 = hsv[(size_t)s0 * 8 + jj];
            uint4 u1 = hsv[(size_t)s1 * 8 + jj];
            uint4 u2 = hsv[(size_t)s2 * 8 + jj];
            uint4 u3 = hsv[(size_t)s3 * 8 + jj];
            acc8(u0, a);
            acc8(u1, a);
            acc8(u2, a);
            acc8(u3, a);
        }
        for (; q < m; q++) {
            int s = __shfl(c, gb + q);
            acc8(hsv[(size_t)s * 8 + jj], a);
        }
    }
    float d = dis[i];
    const float4* b4 = (const float4*)bias;
    float4 bb0 = b4[jj * 2];
    float4 bb1 = b4[jj * 2 + 1];
    float4 o0, o1;
    o0.x = d * a[0] + bb0.x; o0.y = d * a[1] + bb0.y;
    o0.z = d * a[2] + bb0.z; o0.w = d * a[3] + bb0.w;
    o1.x = d * a[4] + bb1.x; o1.y = d * a[5] + bb1.y;
    o1.z = d * a[6] + bb1.z; o1.w = d * a[7] + bb1.w;
    if (RELU) {
        o0.x = fmaxf(o0.x, 0.f); o0.y = fmaxf(o0.y, 0.f);
        o0.z = fmaxf(o0.z, 0.f); o0.w = fmaxf(o0.w, 0.f);
        o1.x = fmaxf(o1.x, 0.f); o1.y = fmaxf(o1.y, 0.f);
        o1.z = fmaxf(o1.z, 0.f); o1.w = fmaxf(o1.w, 0.f);
    }
    float4* orow = (float4*)out + (size_t)i * 16 + jj * 2;
    orow[0] = o0;
    orow[1] = o1;
}

extern "C" void kernel_launch(void* const* d_in, const int* in_sizes, int n_in,
                              void* d_out, int out_size, void* d_ws, size_t ws_size,
                              hipStream_t stream) {
    const float* x  = (const float*)d_in[0];
    const int*   ei = (const int*)d_in[1];
    const float* W1 = (const float*)d_in[2];
    const float* b1 = (const float*)d_in[3];
    const float* W2 = (const float*)d_in[4];
    const float* b2 = (const float*)d_in[5];

    const int n = in_sizes[0] / 128;
    const int E = in_sizes[1] / 2;
    const int* srcp = ei;
    const int* dstp = ei + E;

    float* out = (float*)d_out;

    const int B = (n + BW - 1) / BW;
    const int nblk = (E + CHUNK - 1) / CHUNK;  // <= 512 required

    // workspace layout
    int*            cnt     = (int*)d_ws;                     // 512*MAXB
    int*            gcnt    = cnt + 512 * MAXB;               // MAXB
    unsigned int*   rowinfo = (unsigned int*)(gcnt + MAXB);   // n
    float*          dis     = (float*)(rowinfo + n);          // n
    int*            ebuf    = (int*)(dis + n);                // B*SLAB (becomes col)
    unsigned short* hs      = (unsigned short*)(ebuf + (size_t)B * SLAB);  // n*64 bf16
    unsigned short* whf1    = hs + (size_t)n * FOUT;          // NT1*8 (16B-aligned)
    unsigned short* wlf1    = whf1 + (size_t)NT1 * 8;
    unsigned short* whf2    = wlf1 + (size_t)NT1 * 8;
    unsigned short* wlf2    = whf2 + (size_t)NT2 * 8;
    unsigned short* hs2     = wlf2 + (size_t)NT2 * 8;         // n*64 bf16

    // deterministic multisplit CSR build (no global atomics anywhere);
    // block 0 of edge_hist also pre-splits W1/W2 into bf16 hi/lo frag tables
    edge_hist<<<nblk, 512, 0, stream>>>(dstp, cnt, E, W1, W2,
                                        whf1, wlf1, whf2, wlf2);
    col_scan<<<B, 512, 0, stream>>>(cnt, nblk, gcnt);
    edge_place<<<nblk, 512, 0, stream>>>(srcp, dstp, cnt, ebuf, E);

    // CSR finalize + gemm1 fused (dis rows are bucket-local)
    csr_gemm<128><<<B, 512, 0, stream>>>(ebuf, gcnt, rowinfo, dis, n,
                                         x, whf1, wlf1, hs);

    // aggregate1 + relu + gemm2 fused (out1 lives only in LDS)
    agg_gemm<<<(n + 31) / 32, 256, 0, stream>>>(
        (const uint4*)hs, rowinfo, ebuf, dis, b1, whf2, wlf2, hs2, n);

    // layer 2 aggregate: out = dis*(hs2_self + sum hs2[nbr]) + b2
    aggregate<false><<<(n + 31) / 32, 256, 0, stream>>>(
        (const uint4*)hs2, rowinfo, ebuf, dis, b2, out, n);
}